// Round 5
// baseline (2016.987 us; speedup 1.0000x reference)
//
#include <hip/hip_runtime.h>

typedef __attribute__((ext_vector_type(8))) short bf16x8;
typedef __attribute__((ext_vector_type(4))) float f32x4;

// LDS map (80 KiB -> 2 blocks/CU):
//  XK 0..32K   : x bf16 [t][chunk16 swz c16^(t&7)]  -> later k [m][chunk swz c16^(m&31)] -> attn-out
//  S  32K..48K : dw-slice [n][c8 swz c8^(n&15)] ; later per-wave v-bounce / P-buf (8 x 2KB)
//  Q  48K..80K : q [n][chunk swz c16^(n&31)]
#define XK_B 0
#define S_B  32768
#define Q_B  49152

__device__ __forceinline__ unsigned short f2b(float f) {
  unsigned int v = __builtin_bit_cast(unsigned int, f);
  v += 0x7FFFu + ((v >> 16) & 1u);
  return (unsigned short)(v >> 16);
}
__device__ __forceinline__ unsigned int pk2(float a, float b) {
  return (unsigned int)f2b(a) | ((unsigned int)f2b(b) << 16);
}
__device__ __forceinline__ bf16x8 pack8(const float4& a, const float4& b) {
  union { unsigned int u[4]; bf16x8 v; } x;
  x.u[0] = pk2(a.x, a.y); x.u[1] = pk2(a.z, a.w);
  x.u[2] = pk2(b.x, b.y); x.u[3] = pk2(b.z, b.w);
  return x.v;
}
__device__ __forceinline__ float lo16(unsigned int u) { return __builtin_bit_cast(float, u << 16); }
__device__ __forceinline__ float hi16(unsigned int u) { return __builtin_bit_cast(float, u & 0xFFFF0000u); }

// one-time: dww [c][tap] -> d_ws [p][tap][c] (f32) for vectorized dw-conv weight loads
__global__ void transpose_dw_kernel(const float* __restrict__ w0,
                                    const float* __restrict__ w1,
                                    const float* __restrict__ w2,
                                    float* __restrict__ out) {
  int i = blockIdx.x * 256 + threadIdx.x;
  if (i >= 6912) return;
  int p = i / 2304, r = i % 2304, tap = r >> 8, c = r & 255;
  const float* w = (p == 0) ? w0 : ((p == 1) ? w1 : w2);
  out[i] = w[c * 9 + tap];
}

template<int USE_WS>
__global__ __launch_bounds__(512, 4) void winattn_kernel(
    const float* __restrict__ xg,
    const float* __restrict__ dww0, const float* __restrict__ dwb0,
    const float* __restrict__ pww0, const float* __restrict__ pwb0,
    const float* __restrict__ dww1, const float* __restrict__ dwb1,
    const float* __restrict__ pww1, const float* __restrict__ pwb1,
    const float* __restrict__ dww2, const float* __restrict__ dwb2,
    const float* __restrict__ pww2, const float* __restrict__ pwb2,
    const float* __restrict__ bt,
    const float* __restrict__ pjw, const float* __restrict__ pjb,
    const int* __restrict__ rel,
    const float* __restrict__ wsT,
    float* __restrict__ outg)
{
  __shared__ __align__(16) unsigned char smem[81920];

  const int tid  = threadIdx.x;
  const int lane = tid & 63;
  const int wv   = tid >> 6;        // wave id = head id
  const int lc   = lane & 15;
  const int lq2  = lane >> 4;       // 0..3
  const int b    = blockIdx.x;
  const float* xb = xg + (size_t)b * 16384;

  const float* dwwA[3] = {dww0, dww1, dww2};
  const float* dwbA[3] = {dwb0, dwb1, dwb2};
  const float* pwwA[3] = {pww0, pww1, pww2};
  const float* pwbA[3] = {pwb0, pwb1, pwb2};

  const f32x4 zero4 = {0.f, 0.f, 0.f, 0.f};

  // ---- stage x once: f32 global -> bf16 LDS, swizzled 16B chunks ----
#pragma unroll
  for (int it = 0; it < 4; ++it) {
    const int g   = tid + it * 512;        // 2048 granules = 64 n x 32 chunks
    const int n   = g >> 5;
    const int c16 = g & 31;
    const float4 wa = *(const float4*)(xb + n * 256 + c16 * 8);
    const float4 wb = *(const float4*)(xb + n * 256 + c16 * 8 + 4);
    *(bf16x8*)(smem + XK_B + n * 512 + ((c16 ^ (n & 7))) * 16) = pack8(wa, wb);
  }
  __syncthreads();

  // ---- depthwise 3x3 + bias + relu for one 128-ch slice; x from LDS ----
  auto dwconv = [&](int p, int s) {
    const int c8    = tid & 15;           // octet within slice
    const int strip = tid >> 4;           // 0..31
    const int l = strip >> 2, w0 = (strip & 3) * 2;
    const int n0  = l * 8 + w0;
    const int c16 = s * 16 + c8;          // x chunk index
    const int cb  = s * 128 + c8 * 8;     // global channel base (8 ch)
    float o0[8], o1[8];
    {
      const f32x4 b0 = *(const f32x4*)(dwbA[p] + cb);
      const f32x4 b1 = *(const f32x4*)(dwbA[p] + cb + 4);
#pragma unroll
      for (int j = 0; j < 4; ++j) { o0[j] = b0[j]; o1[j] = o0[j]; }
#pragma unroll
      for (int j = 0; j < 4; ++j) { o0[4 + j] = b1[j]; o1[4 + j] = o0[4 + j]; }
    }
#pragma unroll
    for (int dl = 0; dl < 3; ++dl) {
      const int row = l + dl - 1;
      const bool rok = (row >= 0) && (row < 8);
      float xr[4][8];
#pragma unroll
      for (int wn = 0; wn < 4; ++wn) {
        const int col = w0 + wn - 1;
        if (rok && col >= 0 && col < 8) {
          const int t = row * 8 + col;
          const uint4 u = *(const uint4*)(smem + XK_B + t * 512 + ((c16 ^ (t & 7))) * 16);
          xr[wn][0] = lo16(u.x); xr[wn][1] = hi16(u.x);
          xr[wn][2] = lo16(u.y); xr[wn][3] = hi16(u.y);
          xr[wn][4] = lo16(u.z); xr[wn][5] = hi16(u.z);
          xr[wn][6] = lo16(u.w); xr[wn][7] = hi16(u.w);
        } else {
#pragma unroll
          for (int j = 0; j < 8; ++j) xr[wn][j] = 0.f;
        }
      }
#pragma unroll
      for (int dc = 0; dc < 3; ++dc) {
        float wt[8];
        if (USE_WS) {
          const float* wrow = wsT + (p * 9 + dl * 3 + dc) * 256 + cb;
          const f32x4 wv0 = *(const f32x4*)(wrow);
          const f32x4 wv1 = *(const f32x4*)(wrow + 4);
#pragma unroll
          for (int j = 0; j < 4; ++j) { wt[j] = wv0[j]; wt[4 + j] = wv1[j]; }
        } else {
          const float* wp = dwwA[p];
#pragma unroll
          for (int j = 0; j < 8; ++j) wt[j] = wp[(cb + j) * 9 + dl * 3 + dc];
        }
#pragma unroll
        for (int j = 0; j < 8; ++j) {
          o0[j] = fmaf(wt[j], xr[dc][j], o0[j]);
          o1[j] = fmaf(wt[j], xr[dc + 1][j], o1[j]);
        }
      }
    }
    union { unsigned int u[4]; bf16x8 v; } y0, y1;
#pragma unroll
    for (int j = 0; j < 4; ++j) {
      y0.u[j] = pk2(fmaxf(o0[2 * j], 0.f), fmaxf(o0[2 * j + 1], 0.f));
      y1.u[j] = pk2(fmaxf(o1[2 * j], 0.f), fmaxf(o1[2 * j + 1], 0.f));
    }
    const int n1 = n0 + 1;
    *(bf16x8*)(smem + S_B + n0 * 256 + ((c8 ^ (n0 & 15)) & 15) * 16) = y0.v;
    *(bf16x8*)(smem + S_B + n1 * 256 + ((c8 ^ (n1 & 15)) & 15) * 16) = y1.v;
  };

  // =============== phase V (branch 2): pw normal orientation, v -> registers ===============
  bf16x8 vfrag[2][2];
  {
    f32x4 av[4][2];
#pragma unroll
    for (int i = 0; i < 4; ++i)
#pragma unroll
      for (int t = 0; t < 2; ++t) av[i][t] = zero4;

    for (int s = 0; s < 2; ++s) {
      dwconv(2, s);
      __syncthreads();
      const float* W = pwwA[2];
#pragma unroll
      for (int kk = 0; kk < 4; ++kk) {
        bf16x8 afr[4];
#pragma unroll
        for (int i = 0; i < 4; ++i) {
          const int m = 16 * i + lc;
          afr[i] = *(const bf16x8*)(smem + S_B + m * 256 + (((4 * kk + lq2) ^ (m & 15)) & 15) * 16);
        }
        bf16x8 bb[2];
#pragma unroll
        for (int t = 0; t < 2; ++t) {
          const int co = 16 * (2 * wv + t) + lc;
          const int ci0 = s * 128 + 32 * kk + 8 * lq2;
          const float4 wa = *(const float4*)(W + co * 256 + ci0);
          const float4 wb = *(const float4*)(W + co * 256 + ci0 + 4);
          bb[t] = pack8(wa, wb);
        }
#pragma unroll
        for (int i = 0; i < 4; ++i)
#pragma unroll
          for (int t = 0; t < 2; ++t)
            av[i][t] = __builtin_amdgcn_mfma_f32_16x16x32_bf16(afr[i], bb[t], av[i][t], 0, 0, 0);
      }
      __syncthreads();
    }
    // epilogue: +bias; per-wave v^T bounce through S (2KB/wave), two half-rounds
#pragma unroll
    for (int t = 0; t < 2; ++t) {
      const float pb = pwbA[2][16 * (2 * wv + t) + lc];
#pragma unroll
      for (int i = 0; i < 4; ++i) {
        const int m0 = 16 * i + 4 * lq2;
        uint2 u;
        u.x = pk2(av[i][t][0] + pb, av[i][t][1] + pb);
        u.y = pk2(av[i][t][2] + pb, av[i][t][3] + pb);
        *(uint2*)(smem + S_B + wv * 2048 + lc * 128 +
                  (((m0 >> 3) ^ (lc & 7)) & 7) * 16 + (lq2 & 1) * 8) = u;
      }
#pragma unroll
      for (int kk = 0; kk < 2; ++kk)
        vfrag[t][kk] = *(const bf16x8*)(smem + S_B + wv * 2048 + lc * 128 +
                                        (((4 * kk + lq2) ^ (lc & 7)) & 7) * 16);
    }
  }
  __syncthreads();   // protect per-wave v-bounce region from Q's dwconv slice writes

  // =============== phases Q (branch 0) and K (branch 1): transposed pw ===============
  for (int qk = 0; qk < 2; ++qk) {
    const int dstB = qk ? XK_B : Q_B;    // k overwrites x (dead after last dwconv)
    f32x4 acc[2][4];
#pragma unroll
    for (int cot = 0; cot < 2; ++cot)
#pragma unroll
      for (int nt = 0; nt < 4; ++nt) acc[cot][nt] = zero4;

    for (int s = 0; s < 2; ++s) {
      dwconv(qk, s);
      __syncthreads();
      const float* W = pwwA[qk];
#pragma unroll
      for (int kk = 0; kk < 4; ++kk) {
        bf16x8 afrW[2];
#pragma unroll
        for (int cot = 0; cot < 2; ++cot) {
          const int co = 32 * wv + 16 * cot + lc;
          const int ci0 = s * 128 + 32 * kk + 8 * lq2;
          const float4 wa = *(const float4*)(W + co * 256 + ci0);
          const float4 wb = *(const float4*)(W + co * 256 + ci0 + 4);
          afrW[cot] = pack8(wa, wb);
        }
        bf16x8 bfr[4];
#pragma unroll
        for (int nt = 0; nt < 4; ++nt) {
          const int n = 16 * nt + lc;
          bfr[nt] = *(const bf16x8*)(smem + S_B + n * 256 + (((4 * kk + lq2) ^ (n & 15)) & 15) * 16);
        }
#pragma unroll
        for (int cot = 0; cot < 2; ++cot)
#pragma unroll
          for (int nt = 0; nt < 4; ++nt)
            acc[cot][nt] = __builtin_amdgcn_mfma_f32_16x16x32_bf16(afrW[cot], bfr[nt], acc[cot][nt], 0, 0, 0);
      }
      __syncthreads();
    }
    // epilogue: +bias, b64 stores into [n][c16 swz] region
#pragma unroll
    for (int cot = 0; cot < 2; ++cot) {
      const int c0 = 32 * wv + 16 * cot + 4 * lq2;
      float pb[4];
#pragma unroll
      for (int r = 0; r < 4; ++r) pb[r] = pwbA[qk][c0 + r];
#pragma unroll
      for (int nt = 0; nt < 4; ++nt) {
        const int n = 16 * nt + lc;
        uint2 u;
        u.x = pk2(acc[cot][nt][0] + pb[0], acc[cot][nt][1] + pb[1]);
        u.y = pk2(acc[cot][nt][2] + pb[2], acc[cot][nt][3] + pb[3]);
        *(uint2*)(smem + dstB + n * 512 + (((c0 >> 3) ^ (n & 31)) & 31) * 16 + (lq2 & 1) * 8) = u;
      }
    }
  }

  // =============== attention (wave-local; head h = wv) ===============
  {
    const int h = wv;
    bf16x8 kfrag[4];
#pragma unroll
    for (int mt = 0; mt < 4; ++mt) {
      const int m = 16 * mt + lc;
      kfrag[mt] = *(const bf16x8*)(smem + XK_B + m * 512 + (((4 * h + lq2) ^ (m & 31)) & 31) * 16);
    }
    const float scale = 0.17677669529663687f;
#pragma unroll
    for (int qt = 0; qt < 4; ++qt) {
      const int n = 16 * qt + lc;
      const bf16x8 qfrag = *(const bf16x8*)(smem + Q_B + n * 512 + (((4 * h + lq2) ^ (n & 31)) & 31) * 16);
      f32x4 sc[4];
#pragma unroll
      for (int mt = 0; mt < 4; ++mt)
        sc[mt] = __builtin_amdgcn_mfma_f32_16x16x32_bf16(kfrag[mt], qfrag, zero4, 0, 0, 0);
      const int* relrow = rel + n * 64;
      float sv[4][4];
#pragma unroll
      for (int mt = 0; mt < 4; ++mt)
#pragma unroll
        for (int r = 0; r < 4; ++r) {
          const int m = 16 * mt + 4 * lq2 + r;
          sv[mt][r] = sc[mt][r] * scale + bt[relrow[m] * 8 + h];
        }
      float mx = sv[0][0];
#pragma unroll
      for (int mt = 0; mt < 4; ++mt)
#pragma unroll
        for (int r = 0; r < 4; ++r) mx = fmaxf(mx, sv[mt][r]);
      mx = fmaxf(mx, __shfl_xor(mx, 16));
      mx = fmaxf(mx, __shfl_xor(mx, 32));
      float sum = 0.f;
#pragma unroll
      for (int mt = 0; mt < 4; ++mt)
#pragma unroll
        for (int r = 0; r < 4; ++r) {
          sv[mt][r] = __expf(sv[mt][r] - mx);
          sum += sv[mt][r];
        }
      sum += __shfl_xor(sum, 16);
      sum += __shfl_xor(sum, 32);
      const float rinv = __builtin_amdgcn_rcpf(sum);
#pragma unroll
      for (int mt = 0; mt < 4; ++mt) {
        const int m0 = 16 * mt + 4 * lq2;
        uint2 u;
        u.x = pk2(sv[mt][0], sv[mt][1]);
        u.y = pk2(sv[mt][2], sv[mt][3]);
        *(uint2*)(smem + S_B + wv * 2048 + lc * 128 +
                  (((m0 >> 3) ^ (lc & 7)) & 7) * 16 + (lq2 & 1) * 8) = u;
      }
      f32x4 o[2] = {zero4, zero4};
#pragma unroll
      for (int kk = 0; kk < 2; ++kk) {
        const bf16x8 pf = *(const bf16x8*)(smem + S_B + wv * 2048 + lc * 128 +
                                           (((4 * kk + lq2) ^ (lc & 7)) & 7) * 16);
#pragma unroll
        for (int ct = 0; ct < 2; ++ct)
          o[ct] = __builtin_amdgcn_mfma_f32_16x16x32_bf16(vfrag[ct][kk], pf, o[ct], 0, 0, 0);
      }
#pragma unroll
      for (int ct = 0; ct < 2; ++ct) {
        const int c0 = 32 * h + 16 * ct + 4 * lq2;
        uint2 u;
        u.x = pk2(o[ct][0] * rinv, o[ct][1] * rinv);
        u.y = pk2(o[ct][2] * rinv, o[ct][3] * rinv);
        *(uint2*)(smem + XK_B + n * 512 + (((c0 >> 3) ^ (n & 31)) & 31) * 16 + (lq2 & 1) * 8) = u;
      }
    }
  }
  __syncthreads();

  // =============== projection GEMM + bias -> global f32 ===============
  {
    f32x4 pacc[4][2];
#pragma unroll
    for (int i = 0; i < 4; ++i)
#pragma unroll
      for (int t = 0; t < 2; ++t) pacc[i][t] = zero4;
#pragma unroll
    for (int kk = 0; kk < 8; ++kk) {
      bf16x8 afr[4];
#pragma unroll
      for (int i = 0; i < 4; ++i) {
        const int n = 16 * i + lc;
        afr[i] = *(const bf16x8*)(smem + XK_B + n * 512 + (((4 * kk + lq2) ^ (n & 31)) & 31) * 16);
      }
      bf16x8 bb[2];
#pragma unroll
      for (int t = 0; t < 2; ++t) {
        const int co = 16 * (2 * wv + t) + lc;
        const float4 wa = *(const float4*)(pjw + co * 256 + 32 * kk + 8 * lq2);
        const float4 wb = *(const float4*)(pjw + co * 256 + 32 * kk + 8 * lq2 + 4);
        bb[t] = pack8(wa, wb);
      }
#pragma unroll
      for (int i = 0; i < 4; ++i)
#pragma unroll
        for (int t = 0; t < 2; ++t)
          pacc[i][t] = __builtin_amdgcn_mfma_f32_16x16x32_bf16(afr[i], bb[t], pacc[i][t], 0, 0, 0);
    }
    float* og = outg + (size_t)b * 16384;
#pragma unroll
    for (int t = 0; t < 2; ++t) {
      const int co = 16 * (2 * wv + t) + lc;
      const float pbv = pjb[co];
#pragma unroll
      for (int i = 0; i < 4; ++i)
#pragma unroll
        for (int r = 0; r < 4; ++r)
          og[(16 * i + 4 * lq2 + r) * 256 + co] = pacc[i][t][r] + pbv;
    }
  }
}

extern "C" void kernel_launch(void* const* d_in, const int* in_sizes, int n_in,
                              void* d_out, int out_size, void* d_ws, size_t ws_size,
                              hipStream_t stream) {
  (void)in_sizes; (void)n_in; (void)out_size;
  const float* x    = (const float*)d_in[0];
  const float* qdww = (const float*)d_in[1];
  const float* qdwb = (const float*)d_in[2];
  const float* qpww = (const float*)d_in[3];
  const float* qpwb = (const float*)d_in[4];
  const float* kdww = (const float*)d_in[5];
  const float* kdwb = (const float*)d_in[6];
  const float* kpww = (const float*)d_in[7];
  const float* kpwb = (const float*)d_in[8];
  const float* vdww = (const float*)d_in[9];
  const float* vdwb = (const float*)d_in[10];
  const float* vpww = (const float*)d_in[11];
  const float* vpwb = (const float*)d_in[12];
  const float* bt   = (const float*)d_in[13];
  const float* pjw  = (const float*)d_in[14];
  const float* pjb  = (const float*)d_in[15];
  const int* rel    = (const int*)d_in[16];
  float* out        = (float*)d_out;

  const bool use_ws = (ws_size >= 6912 * sizeof(float)) && (d_ws != nullptr);
  float* wsT = (float*)d_ws;

  if (use_ws) {
    hipLaunchKernelGGL(transpose_dw_kernel, dim3(27), dim3(256), 0, stream,
                       qdww, kdww, vdww, wsT);
    hipLaunchKernelGGL((winattn_kernel<1>), dim3(4096), dim3(512), 0, stream,
                       x, qdww, qdwb, qpww, qpwb, kdww, kdwb, kpww, kpwb,
                       vdww, vdwb, vpww, vpwb, bt, pjw, pjb, rel, wsT, out);
  } else {
    hipLaunchKernelGGL((winattn_kernel<0>), dim3(4096), dim3(512), 0, stream,
                       x, qdww, qdwb, qpww, qpwb, kdww, kdwb, kpww, kpwb,
                       vdww, vdwb, vpww, vpwb, bt, pjw, pjb, rel, (const float*)nullptr, out);
  }
}

// Round 6
// 1110.633 us; speedup vs baseline: 1.8161x; 1.8161x over previous
//
#include <hip/hip_runtime.h>

typedef __attribute__((ext_vector_type(8))) short bf16x8;
typedef __attribute__((ext_vector_type(4))) float f32x4;

// LDS map (80 KiB -> 2 blocks/CU):
//  XK 0..32K   : x bf16 [t][chunk16 swz c16^(t&7)]  -> later k [m][chunk swz] -> attn-out
//  S  32K..48K : dw-slice [n][c8 swz c8^(n&15)] ; later per-wave v-bounce / P-buf (8 x 2KB)
//  Q  48K..80K : q [n][chunk swz c16^(n&31)]
#define XK_B 0
#define S_B  32768
#define Q_B  49152

__device__ __forceinline__ unsigned short f2b(float f) {
  unsigned int v = __builtin_bit_cast(unsigned int, f);
  v += 0x7FFFu + ((v >> 16) & 1u);
  return (unsigned short)(v >> 16);
}
__device__ __forceinline__ unsigned int pk2(float a, float b) {
  return (unsigned int)f2b(a) | ((unsigned int)f2b(b) << 16);
}
__device__ __forceinline__ bf16x8 pack8(const float4& a, const float4& b) {
  union { unsigned int u[4]; bf16x8 v; } x;
  x.u[0] = pk2(a.x, a.y); x.u[1] = pk2(a.z, a.w);
  x.u[2] = pk2(b.x, b.y); x.u[3] = pk2(b.z, b.w);
  return x.v;
}
__device__ __forceinline__ float lo16(unsigned int u) { return __builtin_bit_cast(float, u << 16); }
__device__ __forceinline__ float hi16(unsigned int u) { return __builtin_bit_cast(float, u & 0xFFFF0000u); }

// one-time: dww [c][tap] -> d_ws [p][tap][c] (f32) for vectorized dw-conv weight loads
__global__ void transpose_dw_kernel(const float* __restrict__ w0,
                                    const float* __restrict__ w1,
                                    const float* __restrict__ w2,
                                    float* __restrict__ out) {
  int i = blockIdx.x * 256 + threadIdx.x;
  if (i >= 6912) return;
  int p = i / 2304, r = i % 2304, tap = r >> 8, c = r & 255;
  const float* w = (p == 0) ? w0 : ((p == 1) ? w1 : w2);
  out[i] = w[c * 9 + tap];
}

template<int USE_WS>
__global__ __launch_bounds__(512, 2) void winattn_kernel(
    const float* __restrict__ xg,
    const float* __restrict__ dww0, const float* __restrict__ dwb0,
    const float* __restrict__ pww0, const float* __restrict__ pwb0,
    const float* __restrict__ dww1, const float* __restrict__ dwb1,
    const float* __restrict__ pww1, const float* __restrict__ pwb1,
    const float* __restrict__ dww2, const float* __restrict__ dwb2,
    const float* __restrict__ pww2, const float* __restrict__ pwb2,
    const float* __restrict__ bt,
    const float* __restrict__ pjw, const float* __restrict__ pjb,
    const int* __restrict__ rel,
    const float* __restrict__ wsT,
    float* __restrict__ outg)
{
  __shared__ __align__(16) unsigned char smem[81920];

  const int tid  = threadIdx.x;
  const int lane = tid & 63;
  const int wv   = tid >> 6;        // wave id = head id
  const int lc   = lane & 15;
  const int lq2  = lane >> 4;       // 0..3
  const int b    = blockIdx.x;
  const float* xb = xg + (size_t)b * 16384;

  const f32x4 zero4 = {0.f, 0.f, 0.f, 0.f};

  // ---- stage x once: f32 global -> bf16 LDS, swizzled 16B chunks ----
#pragma unroll
  for (int it = 0; it < 4; ++it) {
    const int g   = tid + it * 512;        // 2048 granules = 64 n x 32 chunks
    const int n   = g >> 5;
    const int c16 = g & 31;
    const float4 wa = *(const float4*)(xb + n * 256 + c16 * 8);
    const float4 wb = *(const float4*)(xb + n * 256 + c16 * 8 + 4);
    *(bf16x8*)(smem + XK_B + n * 512 + ((c16 ^ (n & 7))) * 16) = pack8(wa, wb);
  }
  __syncthreads();

  // ---- depthwise 3x3 + bias + relu, one 128-ch slice; rolling-column, low pressure ----
  // dwwT: [tap][c] transposed weights (USE_WS), dwwR: raw [c][tap] fallback
  auto dwconv = [&](int s, const float* __restrict__ dwb,
                    const float* __restrict__ dwwT, const float* __restrict__ dwwR) {
    const int c8    = tid & 15;           // octet within slice
    const int strip = tid >> 4;           // 0..31
    const int l = strip >> 2, w0c = (strip & 3) * 2;
    const int n0  = l * 8 + w0c;
    const int c16 = s * 16 + c8;          // x chunk index
    const int cb  = s * 128 + c8 * 8;     // global channel base (8 ch)
    float o0[8], o1[8];
    {
      const f32x4 b0 = *(const f32x4*)(dwb + cb);
      const f32x4 b1 = *(const f32x4*)(dwb + cb + 4);
#pragma unroll
      for (int j = 0; j < 4; ++j) {
        o0[j] = b0[j]; o1[j] = b0[j];
        o0[4 + j] = b1[j]; o1[4 + j] = b1[j];
      }
    }
#pragma unroll
    for (int dl = 0; dl < 3; ++dl) {
      const int row = l + dl - 1;
      const bool rok = (row >= 0) && (row < 8);
      float wt[3][8];
#pragma unroll
      for (int dc = 0; dc < 3; ++dc) {
        if (USE_WS) {
          const float* wrow = dwwT + (dl * 3 + dc) * 256 + cb;
          const f32x4 wv0 = *(const f32x4*)(wrow);
          const f32x4 wv1 = *(const f32x4*)(wrow + 4);
#pragma unroll
          for (int j = 0; j < 4; ++j) { wt[dc][j] = wv0[j]; wt[dc][4 + j] = wv1[j]; }
        } else {
#pragma unroll
          for (int j = 0; j < 8; ++j) wt[dc][j] = dwwR[(cb + j) * 9 + dl * 3 + dc];
        }
      }
#pragma unroll
      for (int jc = 0; jc < 4; ++jc) {           // rolling column: one xc live at a time
        const int col = w0c + jc - 1;
        float xc[8];
        if (rok && col >= 0 && col < 8) {
          const int t = row * 8 + col;
          const uint4 u = *(const uint4*)(smem + XK_B + t * 512 + ((c16 ^ (t & 7))) * 16);
          xc[0] = lo16(u.x); xc[1] = hi16(u.x);
          xc[2] = lo16(u.y); xc[3] = hi16(u.y);
          xc[4] = lo16(u.z); xc[5] = hi16(u.z);
          xc[6] = lo16(u.w); xc[7] = hi16(u.w);
        } else {
#pragma unroll
          for (int j = 0; j < 8; ++j) xc[j] = 0.f;
        }
        if (jc < 3) {
#pragma unroll
          for (int j = 0; j < 8; ++j) o0[j] = fmaf(wt[jc][j], xc[j], o0[j]);
        }
        if (jc >= 1) {
#pragma unroll
          for (int j = 0; j < 8; ++j) o1[j] = fmaf(wt[jc - 1][j], xc[j], o1[j]);
        }
      }
    }
    union { unsigned int u[4]; bf16x8 v; } y0, y1;
#pragma unroll
    for (int j = 0; j < 4; ++j) {
      y0.u[j] = pk2(fmaxf(o0[2 * j], 0.f), fmaxf(o0[2 * j + 1], 0.f));
      y1.u[j] = pk2(fmaxf(o1[2 * j], 0.f), fmaxf(o1[2 * j + 1], 0.f));
    }
    const int n1 = n0 + 1;
    *(bf16x8*)(smem + S_B + n0 * 256 + ((c8 ^ (n0 & 15)) & 15) * 16) = y0.v;
    *(bf16x8*)(smem + S_B + n1 * 256 + ((c8 ^ (n1 & 15)) & 15) * 16) = y1.v;
  };

  // =============== phase V (branch 2): pw normal orientation, v -> registers ===============
  bf16x8 vfrag[2][2];
  {
    f32x4 av[4][2];
#pragma unroll
    for (int i = 0; i < 4; ++i)
#pragma unroll
      for (int t = 0; t < 2; ++t) av[i][t] = zero4;

#pragma unroll
    for (int s = 0; s < 2; ++s) {
      dwconv(s, dwb2, USE_WS ? (wsT + 2 * 2304) : nullptr, dww2);
      __syncthreads();
      const float* W = pww2;
#pragma unroll
      for (int kk = 0; kk < 4; ++kk) {
        bf16x8 afr[4];
#pragma unroll
        for (int i = 0; i < 4; ++i) {
          const int m = 16 * i + lc;
          afr[i] = *(const bf16x8*)(smem + S_B + m * 256 + (((4 * kk + lq2) ^ (m & 15)) & 15) * 16);
        }
        bf16x8 bb[2];
#pragma unroll
        for (int t = 0; t < 2; ++t) {
          const int co = 16 * (2 * wv + t) + lc;
          const int ci0 = s * 128 + 32 * kk + 8 * lq2;
          const float4 wa = *(const float4*)(W + co * 256 + ci0);
          const float4 wb = *(const float4*)(W + co * 256 + ci0 + 4);
          bb[t] = pack8(wa, wb);
        }
#pragma unroll
        for (int i = 0; i < 4; ++i)
#pragma unroll
          for (int t = 0; t < 2; ++t)
            av[i][t] = __builtin_amdgcn_mfma_f32_16x16x32_bf16(afr[i], bb[t], av[i][t], 0, 0, 0);
      }
      __syncthreads();
    }
    // epilogue: +bias; per-wave v^T bounce through S (2KB/wave), two half-rounds
#pragma unroll
    for (int t = 0; t < 2; ++t) {
      const float pb = pwb2[16 * (2 * wv + t) + lc];
#pragma unroll
      for (int i = 0; i < 4; ++i) {
        const int m0 = 16 * i + 4 * lq2;
        uint2 u;
        u.x = pk2(av[i][t][0] + pb, av[i][t][1] + pb);
        u.y = pk2(av[i][t][2] + pb, av[i][t][3] + pb);
        *(uint2*)(smem + S_B + wv * 2048 + lc * 128 +
                  (((m0 >> 3) ^ (lc & 7)) & 7) * 16 + (lq2 & 1) * 8) = u;
      }
#pragma unroll
      for (int kk = 0; kk < 2; ++kk)
        vfrag[t][kk] = *(const bf16x8*)(smem + S_B + wv * 2048 + lc * 128 +
                                        (((4 * kk + lq2) ^ (lc & 7)) & 7) * 16);
    }
  }
  __syncthreads();   // protect per-wave v-bounce region from Q's dwconv slice writes

  // =============== phases Q (branch 0) and K (branch 1): transposed pw ===============
#pragma unroll
  for (int qk = 0; qk < 2; ++qk) {
    const int dstB = qk ? XK_B : Q_B;    // k overwrites x (dead after last dwconv)
    const float* W   = qk ? pww1 : pww0;
    const float* pwb = qk ? pwb1 : pwb0;
    const float* dwb = qk ? dwb1 : dwb0;
    const float* dwT = USE_WS ? (wsT + (qk ? 1 : 0) * 2304) : nullptr;
    const float* dwR = qk ? dww1 : dww0;
    f32x4 acc[2][4];
#pragma unroll
    for (int cot = 0; cot < 2; ++cot)
#pragma unroll
      for (int nt = 0; nt < 4; ++nt) acc[cot][nt] = zero4;

#pragma unroll
    for (int s = 0; s < 2; ++s) {
      dwconv(s, dwb, dwT, dwR);
      __syncthreads();
#pragma unroll
      for (int kk = 0; kk < 4; ++kk) {
        bf16x8 afrW[2];
#pragma unroll
        for (int cot = 0; cot < 2; ++cot) {
          const int co = 32 * wv + 16 * cot + lc;
          const int ci0 = s * 128 + 32 * kk + 8 * lq2;
          const float4 wa = *(const float4*)(W + co * 256 + ci0);
          const float4 wb = *(const float4*)(W + co * 256 + ci0 + 4);
          afrW[cot] = pack8(wa, wb);
        }
        bf16x8 bfr[4];
#pragma unroll
        for (int nt = 0; nt < 4; ++nt) {
          const int n = 16 * nt + lc;
          bfr[nt] = *(const bf16x8*)(smem + S_B + n * 256 + (((4 * kk + lq2) ^ (n & 15)) & 15) * 16);
        }
#pragma unroll
        for (int cot = 0; cot < 2; ++cot)
#pragma unroll
          for (int nt = 0; nt < 4; ++nt)
            acc[cot][nt] = __builtin_amdgcn_mfma_f32_16x16x32_bf16(afrW[cot], bfr[nt], acc[cot][nt], 0, 0, 0);
      }
      __syncthreads();
    }
    // epilogue: +bias, b64 stores into [n][c16 swz] region
#pragma unroll
    for (int cot = 0; cot < 2; ++cot) {
      const int c0 = 32 * wv + 16 * cot + 4 * lq2;
      float pb[4];
#pragma unroll
      for (int r = 0; r < 4; ++r) pb[r] = pwb[c0 + r];
#pragma unroll
      for (int nt = 0; nt < 4; ++nt) {
        const int n = 16 * nt + lc;
        uint2 u;
        u.x = pk2(acc[cot][nt][0] + pb[0], acc[cot][nt][1] + pb[1]);
        u.y = pk2(acc[cot][nt][2] + pb[2], acc[cot][nt][3] + pb[3]);
        *(uint2*)(smem + dstB + n * 512 + (((c0 >> 3) ^ (n & 31)) & 31) * 16 + (lq2 & 1) * 8) = u;
      }
    }
  }

  // =============== attention (wave-local; head h = wv) ===============
  {
    const int h = wv;
    bf16x8 kfrag[4];
#pragma unroll
    for (int mt = 0; mt < 4; ++mt) {
      const int m = 16 * mt + lc;
      kfrag[mt] = *(const bf16x8*)(smem + XK_B + m * 512 + (((4 * h + lq2) ^ (m & 31)) & 31) * 16);
    }
    const float scale = 0.17677669529663687f;
#pragma unroll
    for (int qt = 0; qt < 4; ++qt) {
      const int n = 16 * qt + lc;
      const bf16x8 qfrag = *(const bf16x8*)(smem + Q_B + n * 512 + (((4 * h + lq2) ^ (n & 31)) & 31) * 16);
      f32x4 sc[4];
#pragma unroll
      for (int mt = 0; mt < 4; ++mt)
        sc[mt] = __builtin_amdgcn_mfma_f32_16x16x32_bf16(kfrag[mt], qfrag, zero4, 0, 0, 0);
      const int* relrow = rel + n * 64;
      float sv[4][4];
#pragma unroll
      for (int mt = 0; mt < 4; ++mt)
#pragma unroll
        for (int r = 0; r < 4; ++r) {
          const int m = 16 * mt + 4 * lq2 + r;
          sv[mt][r] = sc[mt][r] * scale + bt[relrow[m] * 8 + h];
        }
      float mx = sv[0][0];
#pragma unroll
      for (int mt = 0; mt < 4; ++mt)
#pragma unroll
        for (int r = 0; r < 4; ++r) mx = fmaxf(mx, sv[mt][r]);
      mx = fmaxf(mx, __shfl_xor(mx, 16));
      mx = fmaxf(mx, __shfl_xor(mx, 32));
      float sum = 0.f;
#pragma unroll
      for (int mt = 0; mt < 4; ++mt)
#pragma unroll
        for (int r = 0; r < 4; ++r) {
          sv[mt][r] = __expf(sv[mt][r] - mx);
          sum += sv[mt][r];
        }
      sum += __shfl_xor(sum, 16);
      sum += __shfl_xor(sum, 32);
      const float rinv = __builtin_amdgcn_rcpf(sum);
#pragma unroll
      for (int mt = 0; mt < 4; ++mt) {
        const int m0 = 16 * mt + 4 * lq2;
        uint2 u;
        u.x = pk2(sv[mt][0], sv[mt][1]);
        u.y = pk2(sv[mt][2], sv[mt][3]);
        *(uint2*)(smem + S_B + wv * 2048 + lc * 128 +
                  (((m0 >> 3) ^ (lc & 7)) & 7) * 16 + (lq2 & 1) * 8) = u;
      }
      f32x4 o[2] = {zero4, zero4};
#pragma unroll
      for (int kk = 0; kk < 2; ++kk) {
        const bf16x8 pf = *(const bf16x8*)(smem + S_B + wv * 2048 + lc * 128 +
                                           (((4 * kk + lq2) ^ (lc & 7)) & 7) * 16);
#pragma unroll
        for (int ct = 0; ct < 2; ++ct)
          o[ct] = __builtin_amdgcn_mfma_f32_16x16x32_bf16(vfrag[ct][kk], pf, o[ct], 0, 0, 0);
      }
#pragma unroll
      for (int ct = 0; ct < 2; ++ct) {
        const int c0 = 32 * h + 16 * ct + 4 * lq2;
        uint2 u;
        u.x = pk2(o[ct][0] * rinv, o[ct][1] * rinv);
        u.y = pk2(o[ct][2] * rinv, o[ct][3] * rinv);
        *(uint2*)(smem + XK_B + n * 512 + (((c0 >> 3) ^ (n & 31)) & 31) * 16 + (lq2 & 1) * 8) = u;
      }
    }
  }
  __syncthreads();

  // =============== projection GEMM + bias -> global f32 ===============
  {
    f32x4 pacc[4][2];
#pragma unroll
    for (int i = 0; i < 4; ++i)
#pragma unroll
      for (int t = 0; t < 2; ++t) pacc[i][t] = zero4;
#pragma unroll
    for (int kk = 0; kk < 8; ++kk) {
      bf16x8 afr[4];
#pragma unroll
      for (int i = 0; i < 4; ++i) {
        const int n = 16 * i + lc;
        afr[i] = *(const bf16x8*)(smem + XK_B + n * 512 + (((4 * kk + lq2) ^ (n & 31)) & 31) * 16);
      }
      bf16x8 bb[2];
#pragma unroll
      for (int t = 0; t < 2; ++t) {
        const int co = 16 * (2 * wv + t) + lc;
        const float4 wa = *(const float4*)(pjw + co * 256 + 32 * kk + 8 * lq2);
        const float4 wb = *(const float4*)(pjw + co * 256 + 32 * kk + 8 * lq2 + 4);
        bb[t] = pack8(wa, wb);
      }
#pragma unroll
      for (int i = 0; i < 4; ++i)
#pragma unroll
        for (int t = 0; t < 2; ++t)
          pacc[i][t] = __builtin_amdgcn_mfma_f32_16x16x32_bf16(afr[i], bb[t], pacc[i][t], 0, 0, 0);
    }
    float* og = outg + (size_t)b * 16384;
#pragma unroll
    for (int t = 0; t < 2; ++t) {
      const int co = 16 * (2 * wv + t) + lc;
      const float pbv = pjb[co];
#pragma unroll
      for (int i = 0; i < 4; ++i)
#pragma unroll
        for (int r = 0; r < 4; ++r)
          og[(16 * i + 4 * lq2 + r) * 256 + co] = pacc[i][t][r] + pbv;
    }
  }
}

extern "C" void kernel_launch(void* const* d_in, const int* in_sizes, int n_in,
                              void* d_out, int out_size, void* d_ws, size_t ws_size,
                              hipStream_t stream) {
  (void)in_sizes; (void)n_in; (void)out_size;
  const float* x    = (const float*)d_in[0];
  const float* qdww = (const float*)d_in[1];
  const float* qdwb = (const float*)d_in[2];
  const float* qpww = (const float*)d_in[3];
  const float* qpwb = (const float*)d_in[4];
  const float* kdww = (const float*)d_in[5];
  const float* kdwb = (const float*)d_in[6];
  const float* kpww = (const float*)d_in[7];
  const float* kpwb = (const float*)d_in[8];
  const float* vdww = (const float*)d_in[9];
  const float* vdwb = (const float*)d_in[10];
  const float* vpww = (const float*)d_in[11];
  const float* vpwb = (const float*)d_in[12];
  const float* bt   = (const float*)d_in[13];
  const float* pjw  = (const float*)d_in[14];
  const float* pjb  = (const float*)d_in[15];
  const int* rel    = (const int*)d_in[16];
  float* out        = (float*)d_out;

  const bool use_ws = (ws_size >= 6912 * sizeof(float)) && (d_ws != nullptr);
  float* wsT = (float*)d_ws;

  if (use_ws) {
    hipLaunchKernelGGL(transpose_dw_kernel, dim3(27), dim3(256), 0, stream,
                       qdww, kdww, vdww, wsT);
    hipLaunchKernelGGL((winattn_kernel<1>), dim3(4096), dim3(512), 0, stream,
                       x, qdww, qdwb, qpww, qpwb, kdww, kdwb, kpww, kpwb,
                       vdww, vdwb, vpww, vpwb, bt, pjw, pjb, rel, wsT, out);
  } else {
    hipLaunchKernelGGL((winattn_kernel<0>), dim3(4096), dim3(512), 0, stream,
                       x, qdww, qdwb, qpww, qpwb, kdww, kdwb, kpww, kpwb,
                       vdww, vdwb, vpww, vpwb, bt, pjw, pjb, rel, (const float*)nullptr, out);
  }
}

// Round 7
// 938.943 us; speedup vs baseline: 2.1481x; 1.1829x over previous
//
#include <hip/hip_runtime.h>

typedef __attribute__((ext_vector_type(8))) short bf16x8;
typedef __attribute__((ext_vector_type(4))) float f32x4;

// LDS map (80 KiB -> 2 blocks/CU):
//  XK 0..32K   : x bf16 [t][chunk16 swz c16^(t&7)]  -> later k [m][chunk swz] -> attn-out
//  S  32K..48K : dw-slice [n][c8 swz c8^(n&15)] ; later per-wave v-bounce / P-buf (8 x 2KB)
//  Q  48K..80K : q [n][chunk swz c16^(n&31)]
#define XK_B 0
#define S_B  32768
#define Q_B  49152

__device__ __forceinline__ unsigned short f2b(float f) {
  unsigned int v = __builtin_bit_cast(unsigned int, f);
  v += 0x7FFFu + ((v >> 16) & 1u);
  return (unsigned short)(v >> 16);
}
__device__ __forceinline__ unsigned int pk2(float a, float b) {
  return (unsigned int)f2b(a) | ((unsigned int)f2b(b) << 16);
}
__device__ __forceinline__ bf16x8 pack8(const float4& a, const float4& b) {
  union { unsigned int u[4]; bf16x8 v; } x;
  x.u[0] = pk2(a.x, a.y); x.u[1] = pk2(a.z, a.w);
  x.u[2] = pk2(b.x, b.y); x.u[3] = pk2(b.z, b.w);
  return x.v;
}
__device__ __forceinline__ float lo16(unsigned int u) { return __builtin_bit_cast(float, u << 16); }
__device__ __forceinline__ float hi16(unsigned int u) { return __builtin_bit_cast(float, u & 0xFFFF0000u); }

// one-time: dww [c][tap] -> d_ws [p][tap][c] (f32) for vectorized dw-conv weight loads
__global__ void transpose_dw_kernel(const float* __restrict__ w0,
                                    const float* __restrict__ w1,
                                    const float* __restrict__ w2,
                                    float* __restrict__ out) {
  int i = blockIdx.x * 256 + threadIdx.x;
  if (i >= 6912) return;
  int p = i / 2304, r = i % 2304, tap = r >> 8, c = r & 255;
  const float* w = (p == 0) ? w0 : ((p == 1) ? w1 : w2);
  out[i] = w[c * 9 + tap];
}

template<int USE_WS>
__global__ __launch_bounds__(512, 2) void winattn_kernel(
    const float* __restrict__ xg,
    const float* __restrict__ dww0, const float* __restrict__ dwb0,
    const float* __restrict__ pww0, const float* __restrict__ pwb0,
    const float* __restrict__ dww1, const float* __restrict__ dwb1,
    const float* __restrict__ pww1, const float* __restrict__ pwb1,
    const float* __restrict__ dww2, const float* __restrict__ dwb2,
    const float* __restrict__ pww2, const float* __restrict__ pwb2,
    const float* __restrict__ bt,
    const float* __restrict__ pjw, const float* __restrict__ pjb,
    const int* __restrict__ rel,
    const float* __restrict__ wsT,
    float* __restrict__ outg)
{
  __shared__ __align__(16) unsigned char smem[81920];

  const int tid  = threadIdx.x;
  const int lane = tid & 63;
  const int wv   = tid >> 6;        // wave id = head id
  const int lc   = lane & 15;
  const int lq2  = lane >> 4;       // 0..3
  const int b    = blockIdx.x;
  const float* xb = xg + (size_t)b * 16384;

  const f32x4 zero4 = {0.f, 0.f, 0.f, 0.f};

  // ---- stage x once: f32 global -> bf16 LDS, swizzled 16B chunks ----
#pragma unroll
  for (int it = 0; it < 4; ++it) {
    const int g   = tid + it * 512;        // 2048 granules = 64 n x 32 chunks
    const int n   = g >> 5;
    const int c16 = g & 31;
    const float4 wa = *(const float4*)(xb + n * 256 + c16 * 8);
    const float4 wb = *(const float4*)(xb + n * 256 + c16 * 8 + 4);
    *(bf16x8*)(smem + XK_B + n * 512 + ((c16 ^ (n & 7))) * 16) = pack8(wa, wb);
  }
  __syncthreads();

  // ---- depthwise 3x3 + bias + relu, one 128-ch slice; 4 ch/thread, 4 tokens/thread ----
  auto dwconv = [&](int s, const float* __restrict__ dwb,
                    const float* __restrict__ dwwT, const float* __restrict__ dwwR) {
    const int c4    = tid & 31;           // 4-ch slot (32 x 4 = 128 ch)
    const int strip = tid >> 5;           // 0..15
    const int l   = strip >> 1;           // row 0..7
    const int w0c = (strip & 1) * 4;      // col base 0 or 4
    const int cb  = s * 128 + c4 * 4;     // global channel base (4 ch)
    const int c16 = s * 16 + (c4 >> 1);   // x chunk index
    const int hb8 = (c4 & 1) * 8;         // byte half within 16B chunk
    float o[4][4];
    {
      const f32x4 bv = *(const f32x4*)(dwb + cb);
#pragma unroll
      for (int t = 0; t < 4; ++t)
#pragma unroll
        for (int j = 0; j < 4; ++j) o[t][j] = bv[j];
    }
#pragma unroll
    for (int dl = 0; dl < 3; ++dl) {
      const int row = l + dl - 1;
      const bool rok = (row >= 0) && (row < 8);
      float wt[3][4];
#pragma unroll
      for (int dc = 0; dc < 3; ++dc) {
        if (USE_WS) {
          const f32x4 wv0 = *(const f32x4*)(dwwT + (dl * 3 + dc) * 256 + cb);
#pragma unroll
          for (int j = 0; j < 4; ++j) wt[dc][j] = wv0[j];
        } else {
#pragma unroll
          for (int j = 0; j < 4; ++j) wt[dc][j] = dwwR[(cb + j) * 9 + dl * 3 + dc];
        }
      }
#pragma unroll
      for (int jc = 0; jc < 6; ++jc) {     // rolling column: single xc[4] live
        const int col = w0c + jc - 1;
        float xc[4];
        if (rok && col >= 0 && col < 8) {
          const int t = row * 8 + col;
          const uint2 u = *(const uint2*)(smem + XK_B + t * 512 + ((c16 ^ (t & 7))) * 16 + hb8);
          xc[0] = lo16(u.x); xc[1] = hi16(u.x);
          xc[2] = lo16(u.y); xc[3] = hi16(u.y);
        } else {
#pragma unroll
          for (int j = 0; j < 4; ++j) xc[j] = 0.f;
        }
#pragma unroll
        for (int dc = 0; dc < 3; ++dc) {
          const int ot = jc - dc;
          if (ot >= 0 && ot < 4) {
#pragma unroll
            for (int j = 0; j < 4; ++j) o[ot][j] = fmaf(wt[dc][j], xc[j], o[ot][j]);
          }
        }
      }
    }
#pragma unroll
    for (int t = 0; t < 4; ++t) {
      const int n = l * 8 + w0c + t;
      uint2 u;
      u.x = pk2(fmaxf(o[t][0], 0.f), fmaxf(o[t][1], 0.f));
      u.y = pk2(fmaxf(o[t][2], 0.f), fmaxf(o[t][3], 0.f));
      *(uint2*)(smem + S_B + n * 256 + (((c4 >> 1) ^ (n & 15)) & 15) * 16 + hb8) = u;
    }
  };

  // =============== phase V (branch 2): pw normal orientation, v -> registers ===============
  bf16x8 vfrag[2][2];
  {
    f32x4 av[4][2];
#pragma unroll
    for (int i = 0; i < 4; ++i)
#pragma unroll
      for (int t = 0; t < 2; ++t) av[i][t] = zero4;

#pragma unroll
    for (int s = 0; s < 2; ++s) {
      dwconv(s, dwb2, USE_WS ? (wsT + 2 * 2304) : nullptr, dww2);
      __syncthreads();
      const float* W = pww2;
#pragma unroll
      for (int kk = 0; kk < 4; ++kk) {
        bf16x8 afr[4];
#pragma unroll
        for (int i = 0; i < 4; ++i) {
          const int m = 16 * i + lc;
          afr[i] = *(const bf16x8*)(smem + S_B + m * 256 + (((4 * kk + lq2) ^ (m & 15)) & 15) * 16);
        }
        bf16x8 bb[2];
#pragma unroll
        for (int t = 0; t < 2; ++t) {
          const int co = 16 * (2 * wv + t) + lc;
          const int ci0 = s * 128 + 32 * kk + 8 * lq2;
          const float4 wa = *(const float4*)(W + co * 256 + ci0);
          const float4 wb = *(const float4*)(W + co * 256 + ci0 + 4);
          bb[t] = pack8(wa, wb);
        }
#pragma unroll
        for (int i = 0; i < 4; ++i)
#pragma unroll
          for (int t = 0; t < 2; ++t)
            av[i][t] = __builtin_amdgcn_mfma_f32_16x16x32_bf16(afr[i], bb[t], av[i][t], 0, 0, 0);
      }
      __syncthreads();
    }
    // epilogue: +bias; per-wave v^T bounce through S (2KB/wave)
#pragma unroll
    for (int t = 0; t < 2; ++t) {
      const float pb = pwb2[16 * (2 * wv + t) + lc];
#pragma unroll
      for (int i = 0; i < 4; ++i) {
        const int m0 = 16 * i + 4 * lq2;
        uint2 u;
        u.x = pk2(av[i][t][0] + pb, av[i][t][1] + pb);
        u.y = pk2(av[i][t][2] + pb, av[i][t][3] + pb);
        *(uint2*)(smem + S_B + wv * 2048 + lc * 128 +
                  (((m0 >> 3) ^ (lc & 7)) & 7) * 16 + (lq2 & 1) * 8) = u;
      }
#pragma unroll
      for (int kk = 0; kk < 2; ++kk)
        vfrag[t][kk] = *(const bf16x8*)(smem + S_B + wv * 2048 + lc * 128 +
                                        (((4 * kk + lq2) ^ (lc & 7)) & 7) * 16);
    }
  }
  __syncthreads();   // protect per-wave v-bounce region from Q's dwconv slice writes

  // =============== phases Q (branch 0) and K (branch 1): transposed pw ===============
#pragma unroll
  for (int qk = 0; qk < 2; ++qk) {
    const int dstB = qk ? XK_B : Q_B;    // k overwrites x (dead after last dwconv)
    const float* W   = qk ? pww1 : pww0;
    const float* pwb = qk ? pwb1 : pwb0;
    const float* dwb = qk ? dwb1 : dwb0;
    const float* dwT = USE_WS ? (wsT + (qk ? 1 : 0) * 2304) : nullptr;
    const float* dwR = qk ? dww1 : dww0;
    f32x4 acc[2][4];
#pragma unroll
    for (int cot = 0; cot < 2; ++cot)
#pragma unroll
      for (int nt = 0; nt < 4; ++nt) acc[cot][nt] = zero4;

#pragma unroll
    for (int s = 0; s < 2; ++s) {
      dwconv(s, dwb, dwT, dwR);
      __syncthreads();
#pragma unroll
      for (int kk = 0; kk < 4; ++kk) {
        bf16x8 afrW[2];
#pragma unroll
        for (int cot = 0; cot < 2; ++cot) {
          const int co = 32 * wv + 16 * cot + lc;
          const int ci0 = s * 128 + 32 * kk + 8 * lq2;
          const float4 wa = *(const float4*)(W + co * 256 + ci0);
          const float4 wb = *(const float4*)(W + co * 256 + ci0 + 4);
          afrW[cot] = pack8(wa, wb);
        }
        bf16x8 bfr[4];
#pragma unroll
        for (int nt = 0; nt < 4; ++nt) {
          const int n = 16 * nt + lc;
          bfr[nt] = *(const bf16x8*)(smem + S_B + n * 256 + (((4 * kk + lq2) ^ (n & 15)) & 15) * 16);
        }
#pragma unroll
        for (int cot = 0; cot < 2; ++cot)
#pragma unroll
          for (int nt = 0; nt < 4; ++nt)
            acc[cot][nt] = __builtin_amdgcn_mfma_f32_16x16x32_bf16(afrW[cot], bfr[nt], acc[cot][nt], 0, 0, 0);
      }
      __syncthreads();
    }
    // epilogue: +bias, b64 stores into [n][c16 swz] region
#pragma unroll
    for (int cot = 0; cot < 2; ++cot) {
      const int c0 = 32 * wv + 16 * cot + 4 * lq2;
      float pb[4];
#pragma unroll
      for (int r = 0; r < 4; ++r) pb[r] = pwb[c0 + r];
#pragma unroll
      for (int nt = 0; nt < 4; ++nt) {
        const int n = 16 * nt + lc;
        uint2 u;
        u.x = pk2(acc[cot][nt][0] + pb[0], acc[cot][nt][1] + pb[1]);
        u.y = pk2(acc[cot][nt][2] + pb[2], acc[cot][nt][3] + pb[3]);
        *(uint2*)(smem + dstB + n * 512 + (((c0 >> 3) ^ (n & 31)) & 31) * 16 + (lq2 & 1) * 8) = u;
      }
    }
  }

  // =============== attention (wave-local; head h = wv) ===============
  {
    const int h = wv;
    bf16x8 kfrag[4];
#pragma unroll
    for (int mt = 0; mt < 4; ++mt) {
      const int m = 16 * mt + lc;
      kfrag[mt] = *(const bf16x8*)(smem + XK_B + m * 512 + (((4 * h + lq2) ^ (m & 31)) & 31) * 16);
    }
    const float scale = 0.17677669529663687f;
#pragma unroll
    for (int qt = 0; qt < 4; ++qt) {
      const int n = 16 * qt + lc;
      const bf16x8 qfrag = *(const bf16x8*)(smem + Q_B + n * 512 + (((4 * h + lq2) ^ (n & 31)) & 31) * 16);
      f32x4 sc[4];
#pragma unroll
      for (int mt = 0; mt < 4; ++mt)
        sc[mt] = __builtin_amdgcn_mfma_f32_16x16x32_bf16(kfrag[mt], qfrag, zero4, 0, 0, 0);
      const int* relrow = rel + n * 64;
      float sv[4][4];
#pragma unroll
      for (int mt = 0; mt < 4; ++mt)
#pragma unroll
        for (int r = 0; r < 4; ++r) {
          const int m = 16 * mt + 4 * lq2 + r;
          sv[mt][r] = sc[mt][r] * scale + bt[relrow[m] * 8 + h];
        }
      float mx = sv[0][0];
#pragma unroll
      for (int mt = 0; mt < 4; ++mt)
#pragma unroll
        for (int r = 0; r < 4; ++r) mx = fmaxf(mx, sv[mt][r]);
      mx = fmaxf(mx, __shfl_xor(mx, 16));
      mx = fmaxf(mx, __shfl_xor(mx, 32));
      float sum = 0.f;
#pragma unroll
      for (int mt = 0; mt < 4; ++mt)
#pragma unroll
        for (int r = 0; r < 4; ++r) {
          sv[mt][r] = __expf(sv[mt][r] - mx);
          sum += sv[mt][r];
        }
      sum += __shfl_xor(sum, 16);
      sum += __shfl_xor(sum, 32);
      const float rinv = __builtin_amdgcn_rcpf(sum);
#pragma unroll
      for (int mt = 0; mt < 4; ++mt) {
        const int m0 = 16 * mt + 4 * lq2;
        uint2 u;
        u.x = pk2(sv[mt][0], sv[mt][1]);
        u.y = pk2(sv[mt][2], sv[mt][3]);
        *(uint2*)(smem + S_B + wv * 2048 + lc * 128 +
                  (((m0 >> 3) ^ (lc & 7)) & 7) * 16 + (lq2 & 1) * 8) = u;
      }
      f32x4 o[2] = {zero4, zero4};
#pragma unroll
      for (int kk = 0; kk < 2; ++kk) {
        const bf16x8 pf = *(const bf16x8*)(smem + S_B + wv * 2048 + lc * 128 +
                                           (((4 * kk + lq2) ^ (lc & 7)) & 7) * 16);
#pragma unroll
        for (int ct = 0; ct < 2; ++ct)
          o[ct] = __builtin_amdgcn_mfma_f32_16x16x32_bf16(vfrag[ct][kk], pf, o[ct], 0, 0, 0);
      }
#pragma unroll
      for (int ct = 0; ct < 2; ++ct) {
        const int c0 = 32 * h + 16 * ct + 4 * lq2;
        uint2 u;
        u.x = pk2(o[ct][0] * rinv, o[ct][1] * rinv);
        u.y = pk2(o[ct][2] * rinv, o[ct][3] * rinv);
        *(uint2*)(smem + XK_B + n * 512 + (((c0 >> 3) ^ (n & 31)) & 31) * 16 + (lq2 & 1) * 8) = u;
      }
    }
  }
  __syncthreads();

  // =============== projection GEMM + bias -> global f32 ===============
  {
    f32x4 pacc[4][2];
#pragma unroll
    for (int i = 0; i < 4; ++i)
#pragma unroll
      for (int t = 0; t < 2; ++t) pacc[i][t] = zero4;
#pragma unroll
    for (int kk = 0; kk < 8; ++kk) {
      bf16x8 afr[4];
#pragma unroll
      for (int i = 0; i < 4; ++i) {
        const int n = 16 * i + lc;
        afr[i] = *(const bf16x8*)(smem + XK_B + n * 512 + (((4 * kk + lq2) ^ (n & 31)) & 31) * 16);
      }
      bf16x8 bb[2];
#pragma unroll
      for (int t = 0; t < 2; ++t) {
        const int co = 16 * (2 * wv + t) + lc;
        const float4 wa = *(const float4*)(pjw + co * 256 + 32 * kk + 8 * lq2);
        const float4 wb = *(const float4*)(pjw + co * 256 + 32 * kk + 8 * lq2 + 4);
        bb[t] = pack8(wa, wb);
      }
#pragma unroll
      for (int i = 0; i < 4; ++i)
#pragma unroll
        for (int t = 0; t < 2; ++t)
          pacc[i][t] = __builtin_amdgcn_mfma_f32_16x16x32_bf16(afr[i], bb[t], pacc[i][t], 0, 0, 0);
    }
    float* og = outg + (size_t)b * 16384;
#pragma unroll
    for (int t = 0; t < 2; ++t) {
      const int co = 16 * (2 * wv + t) + lc;
      const float pbv = pjb[co];
#pragma unroll
      for (int i = 0; i < 4; ++i)
#pragma unroll
        for (int r = 0; r < 4; ++r)
          og[(16 * i + 4 * lq2 + r) * 256 + co] = pacc[i][t][r] + pbv;
    }
  }
}

extern "C" void kernel_launch(void* const* d_in, const int* in_sizes, int n_in,
                              void* d_out, int out_size, void* d_ws, size_t ws_size,
                              hipStream_t stream) {
  (void)in_sizes; (void)n_in; (void)out_size;
  const float* x    = (const float*)d_in[0];
  const float* qdww = (const float*)d_in[1];
  const float* qdwb = (const float*)d_in[2];
  const float* qpww = (const float*)d_in[3];
  const float* qpwb = (const float*)d_in[4];
  const float* kdww = (const float*)d_in[5];
  const float* kdwb = (const float*)d_in[6];
  const float* kpww = (const float*)d_in[7];
  const float* kpwb = (const float*)d_in[8];
  const float* vdww = (const float*)d_in[9];
  const float* vdwb = (const float*)d_in[10];
  const float* vpww = (const float*)d_in[11];
  const float* vpwb = (const float*)d_in[12];
  const float* bt   = (const float*)d_in[13];
  const float* pjw  = (const float*)d_in[14];
  const float* pjb  = (const float*)d_in[15];
  const int* rel    = (const int*)d_in[16];
  float* out        = (float*)d_out;

  const bool use_ws = (ws_size >= 6912 * sizeof(float)) && (d_ws != nullptr);
  float* wsT = (float*)d_ws;

  if (use_ws) {
    hipLaunchKernelGGL(transpose_dw_kernel, dim3(27), dim3(256), 0, stream,
                       qdww, kdww, vdww, wsT);
    hipLaunchKernelGGL((winattn_kernel<1>), dim3(4096), dim3(512), 0, stream,
                       x, qdww, qdwb, qpww, qpwb, kdww, kdwb, kpww, kpwb,
                       vdww, vdwb, vpww, vpwb, bt, pjw, pjb, rel, wsT, out);
  } else {
    hipLaunchKernelGGL((winattn_kernel<0>), dim3(4096), dim3(512), 0, stream,
                       x, qdww, qdwb, qpww, qpwb, kdww, kdwb, kpww, kpwb,
                       vdww, vdwb, vpww, vpwb, bt, pjw, pjb, rel, (const float*)nullptr, out);
  }
}